// Round 1
// baseline (33276.562 us; speedup 1.0000x reference)
//
#include <hip/hip_runtime.h>

#define DM 256
#define NH 4
#define HD 64
#define DEG 32
#define L 33
#define DOUT 128
#define NTHREADS 256

// bf16 helpers: store as ushort, unpack pairs from uint (lo = u<<16, hi = u&0xFFFF0000)
__device__ __forceinline__ float blo(unsigned int u){ union{unsigned int i;float f;}v; v.i=u<<16; return v.f; }
__device__ __forceinline__ float bhi(unsigned int u){ union{unsigned int i;float f;}v; v.i=u&0xFFFF0000u; return v.f; }
__device__ __forceinline__ float b2f(unsigned short u){ union{unsigned int i;float f;}v; v.i=((unsigned int)u)<<16; return v.f; }
__device__ __forceinline__ unsigned short f2b(float f){
  union{float f;unsigned int i;}v; v.f=f;
  unsigned int r=v.i+0x7FFFu+((v.i>>16)&1u);
  return (unsigned short)(r>>16);
}
__device__ __forceinline__ float wred(float x){
  #pragma unroll
  for (int o=32;o>=1;o>>=1) x += __shfl_xor(x,o,64);
  return x;
}
__device__ __forceinline__ float wmax(float x){
  #pragma unroll
  for (int o=32;o>=1;o>>=1) x = fmaxf(x,__shfl_xor(x,o,64));
  return x;
}

__global__ __launch_bounds__(NTHREADS, 2) void smtp_center(
    const float* __restrict__ H,
    const int* __restrict__ dstE,
    const int* __restrict__ centers,
    const float* __restrict__ target,
    const float* __restrict__ ln_in_w,
    const float* __restrict__ ln1_w,
    const float* __restrict__ ln2_w,
    const float* __restrict__ w_qkv,
    const float* __restrict__ b_qkv,
    const float* __restrict__ w_o,
    const float* __restrict__ b_o,
    const float* __restrict__ w_gate,
    const float* __restrict__ w_up,
    const float* __restrict__ w_down,
    const float* __restrict__ w_head,
    const float* __restrict__ b_head,
    float* __restrict__ partial)
{
  // xn / xn2 staging, f32 for FMA-dense GEMM reads (broadcast rows)
  __shared__ float sN[L*DM];                         // 33792 B
  // union region, time-shared across phases:
  //   phase 1/1b + 3d/4 : sXb  bf16 [33][256]                (16896 B)
  //   phase 2           : sQ2/sK2/sV2 bf16 [2][33][64] + sAO bf16 [33][64]  (29568 B)
  //   phase 3b/3c       : sM   bf16 [33][256]                (16896 B)
  __shared__ __align__(16) unsigned char Ubuf[29568];
  __shared__ float sAttn[4*34];
  __shared__ int sIdx[L];
  __shared__ float sRed[4];

  unsigned short* sQ2 = (unsigned short*)Ubuf;            // [2][L][HD]
  unsigned short* sK2 = (unsigned short*)(Ubuf + 8448);
  unsigned short* sV2 = (unsigned short*)(Ubuf + 16896);
  unsigned short* sAO = (unsigned short*)(Ubuf + 25344);  // [L][HD]
  unsigned short* sXb = (unsigned short*)Ubuf;            // [L][DM]
  unsigned short* sM  = (unsigned short*)Ubuf;            // [L][DM]

  const int tid  = threadIdx.x;
  const int lane = tid & 63;
  const int wave = tid >> 6;
  const int bid  = blockIdx.x;

  // Phase 0: star indices (CSR collapses: every node has exactly DEG sorted out-edges)
  if (tid < L) {
    int ctr = centers[bid];
    sIdx[tid] = (tid == 0) ? ctr : dstE[(size_t)ctr*DEG + (tid-1)];
  }
  __syncthreads();

  // Phase 1: gather rows, rmsnorm(ln_in) -> X (sXb bf16), rmsnorm(ln1) -> xn (sN f32)
  for (int r = wave; r < L; r += 4) {
    const float4 x4 = ((const float4*)(H + (size_t)sIdx[r]*DM))[lane];
    float ss = x4.x*x4.x + x4.y*x4.y + x4.z*x4.z + x4.w*x4.w;
    ss = wred(ss);
    const float rs = rsqrtf(ss*(1.f/DM) + 1e-6f);
    const float4 wi = ((const float4*)ln_in_w)[lane];
    const float4 xv = make_float4(x4.x*rs*wi.x, x4.y*rs*wi.y, x4.z*rs*wi.z, x4.w*rs*wi.w);
    float s2 = xv.x*xv.x + xv.y*xv.y + xv.z*xv.z + xv.w*xv.w;
    s2 = wred(s2);
    const float rs2 = rsqrtf(s2*(1.f/DM) + 1e-6f);
    const float4 w1 = ((const float4*)ln1_w)[lane];
    ((float4*)(sN + r*DM))[lane] = make_float4(xv.x*rs2*w1.x, xv.y*rs2*w1.y, xv.z*rs2*w1.z, xv.w*rs2*w1.w);
    ushort4 xb;
    xb.x = f2b(xv.x); xb.y = f2b(xv.y); xb.z = f2b(xv.z); xb.w = f2b(xv.w);
    ((ushort4*)(sXb + r*DM))[lane] = xb;
  }
  __syncthreads();

  // Phase 1b: residual stream column -> registers (thread = column). b_o folded in once.
  float regX[L];
  {
    const float bo = b_o[tid];
    #pragma unroll
    for (int r = 0; r < L; ++r) regX[r] = b2f(sXb[r*DM + tid]) + bo;
  }
  __syncthreads();   // before phase 2 overwrites the sXb region

  // Phase 2: attention, processed 2 heads per outer iteration
  for (int h0 = 0; h0 < NH; h0 += 2) {
    // 2a: QKV for heads h0,h0+1. wave grp 0/1/2 -> Q/K/V column `lane`; weights read 1x.
    if (wave < 3) {
      float acc0[L], acc1[L];
      #pragma unroll
      for (int r = 0; r < L; ++r) { acc0[r] = 0.f; acc1[r] = 0.f; }
      const float* W0 = w_qkv + ((size_t)wave*DM + (size_t)h0*HD + lane)*DM;
      const float* W1 = W0 + (size_t)HD*DM;
      for (int k0 = 0; k0 < DM; k0 += 4) {
        const float4 w0 = *(const float4*)(W0 + k0);
        const float4 w1 = *(const float4*)(W1 + k0);
        #pragma unroll
        for (int r = 0; r < L; ++r) {
          const float4 a = *(const float4*)(sN + r*DM + k0);   // broadcast
          acc0[r] += a.x*w0.x + a.y*w0.y + a.z*w0.z + a.w*w0.w;
          acc1[r] += a.x*w1.x + a.y*w1.y + a.z*w1.z + a.w*w1.w;
        }
      }
      unsigned short* dst = (wave==0) ? sQ2 : (wave==1) ? sK2 : sV2;
      const float bq0 = b_qkv[wave*DM + h0*HD + lane];
      const float bq1 = b_qkv[wave*DM + (h0+1)*HD + lane];
      #pragma unroll
      for (int r = 0; r < L; ++r) {
        dst[(0*L + r)*HD + lane] = f2b(acc0[r] + bq0);
        dst[(1*L + r)*HD + lane] = f2b(acc1[r] + bq1);
      }
    }
    __syncthreads();

    for (int hh = 0; hh < 2; ++hh) {
      const int h = h0 + hh;
      // 2c: scores + softmax + PV. wave per query row; lane = key (scores) then lane = out col (PV)
      for (int qr = wave; qr < L; qr += 4) {
        float s = -INFINITY;
        if (lane < L) {
          const uint4* Qp = (const uint4*)(sQ2 + (hh*L + qr)*HD);
          const uint4* Kp = (const uint4*)(sK2 + (hh*L + lane)*HD);
          float d = 0.f;
          #pragma unroll
          for (int j = 0; j < HD/8; ++j) {
            const uint4 q = Qp[j], k = Kp[j];
            d += blo(q.x)*blo(k.x) + bhi(q.x)*bhi(k.x);
            d += blo(q.y)*blo(k.y) + bhi(q.y)*bhi(k.y);
            d += blo(q.z)*blo(k.z) + bhi(q.z)*bhi(k.z);
            d += blo(q.w)*blo(k.w) + bhi(q.w)*bhi(k.w);
          }
          s = d * 0.125f;
        }
        const float m = wmax(s);
        const float e = (lane < L) ? __expf(s - m) : 0.f;
        const float den = wred(e);
        if (lane < L) sAttn[wave*34 + lane] = e / den;   // wave-private row; in-order LDS within wave
        float acc = 0.f;
        #pragma unroll
        for (int k = 0; k < L; ++k)
          acc += sAttn[wave*34 + k] * b2f(sV2[(hh*L + k)*HD + lane]);
        sAO[qr*HD + lane] = f2b(acc);
      }
      __syncthreads();

      // 2d: regX += AO_h @ w_o[:, h*64:(h+1)*64]^T   (thread = output column)
      {
        const float* wo = w_o + (size_t)tid*DM + h*HD;
        for (int k0 = 0; k0 < HD; k0 += 8) {
          const float4 wa = *(const float4*)(wo + k0);
          const float4 wb = *(const float4*)(wo + k0 + 4);
          #pragma unroll
          for (int r = 0; r < L; ++r) {
            const uint4 a = *(const uint4*)(sAO + r*HD + k0);  // broadcast
            regX[r] += blo(a.x)*wa.x + bhi(a.x)*wa.y
                     + blo(a.y)*wa.z + bhi(a.y)*wa.w
                     + blo(a.z)*wb.x + bhi(a.z)*wb.y
                     + blo(a.w)*wb.z + bhi(a.w)*wb.w;
          }
        }
      }
      __syncthreads();   // protects sAO (next hh) / sQKV (next h0) / sXb (phase 3a)
    }
  }

  // Phase 3a: X -> sXb, then xn2 = rmsnorm(X, ln2) -> sN
  #pragma unroll
  for (int r = 0; r < L; ++r) sXb[r*DM + tid] = f2b(regX[r]);
  __syncthreads();
  for (int r = wave; r < L; r += 4) {
    const ushort4 xb = ((const ushort4*)(sXb + r*DM))[lane];
    const float x0 = b2f(xb.x), x1 = b2f(xb.y), x2 = b2f(xb.z), x3 = b2f(xb.w);
    float ss = x0*x0 + x1*x1 + x2*x2 + x3*x3;
    ss = wred(ss);
    const float rs = rsqrtf(ss*(1.f/DM) + 1e-6f);
    const float4 w2 = ((const float4*)ln2_w)[lane];
    ((float4*)(sN + r*DM))[lane] = make_float4(x0*rs*w2.x, x1*rs*w2.y, x2*rs*w2.z, x3*rs*w2.w);
  }
  __syncthreads();

  // Phase 3b: mid = silu(xn2 @ w_gate^T) * (xn2 @ w_up^T) -> sM (clobbers sXb; X lives in regX)
  {
    float G[L], Uu[L];
    #pragma unroll
    for (int r = 0; r < L; ++r) { G[r] = 0.f; Uu[r] = 0.f; }
    const float* wg = w_gate + (size_t)tid*DM;
    const float* wu = w_up   + (size_t)tid*DM;
    for (int k0 = 0; k0 < DM; k0 += 4) {
      const float4 g4 = *(const float4*)(wg + k0);
      const float4 u4 = *(const float4*)(wu + k0);
      #pragma unroll
      for (int r = 0; r < L; ++r) {
        const float4 a = *(const float4*)(sN + r*DM + k0);   // broadcast
        G[r]  += a.x*g4.x + a.y*g4.y + a.z*g4.z + a.w*g4.w;
        Uu[r] += a.x*u4.x + a.y*u4.y + a.z*u4.z + a.w*u4.w;
      }
    }
    #pragma unroll
    for (int r = 0; r < L; ++r) {
      const float g = G[r];
      const float act = g / (1.f + __expf(-g));
      sM[r*DM + tid] = f2b(act * Uu[r]);
    }
  }
  __syncthreads();

  // Phase 3c: regX += mid @ w_down^T
  {
    const float* wd = w_down + (size_t)tid*DM;
    for (int k0 = 0; k0 < DM; k0 += 8) {
      const float4 wa = *(const float4*)(wd + k0);
      const float4 wb = *(const float4*)(wd + k0 + 4);
      #pragma unroll
      for (int r = 0; r < L; ++r) {
        const uint4 a = *(const uint4*)(sM + r*DM + k0);     // broadcast
        regX[r] += blo(a.x)*wa.x + bhi(a.x)*wa.y
                 + blo(a.y)*wa.z + bhi(a.y)*wa.w
                 + blo(a.z)*wb.x + bhi(a.z)*wb.y
                 + blo(a.w)*wb.z + bhi(a.w)*wb.w;
      }
    }
  }
  __syncthreads();   // all reads of sM done before Z overwrites region

  // Phase 3d: Z -> sXb
  #pragma unroll
  for (int r = 0; r < L; ++r) sXb[r*DM + tid] = f2b(regX[r]);
  __syncthreads();

  // Phase 4: MTP head + MSE on neighbor rows. thread = (j parity, out col c)
  float lsum = 0.f;
  {
    const int c  = tid & (DOUT-1);
    const int j2 = tid >> 7;               // 0..1
    const float* wh = w_head + (size_t)c*DM;
    float acc[16];
    const float bh = b_head[c];
    #pragma unroll
    for (int i = 0; i < 16; ++i) acc[i] = bh;
    for (int k0 = 0; k0 < DM; k0 += 8) {
      const float4 wa = *(const float4*)(wh + k0);
      const float4 wb = *(const float4*)(wh + k0 + 4);
      #pragma unroll
      for (int i = 0; i < 16; ++i) {
        const int r = 1 + j2 + 2*i;
        const uint4 a = *(const uint4*)(sXb + r*DM + k0);    // broadcast
        acc[i] += blo(a.x)*wa.x + bhi(a.x)*wa.y
                + blo(a.y)*wa.z + bhi(a.y)*wa.w
                + blo(a.z)*wb.x + bhi(a.z)*wb.y
                + blo(a.w)*wb.z + bhi(a.w)*wb.w;
      }
    }
    #pragma unroll
    for (int i = 0; i < 16; ++i) {
      const int j = j2 + 2*i;
      const float t = target[(size_t)sIdx[1+j]*DOUT + c];
      const float d = acc[i] - t;
      lsum += d*d;
    }
  }
  lsum = wred(lsum);
  if (lane == 0) sRed[wave] = lsum;
  __syncthreads();
  if (tid == 0)
    partial[bid] = (sRed[0]+sRed[1]+sRed[2]+sRed[3]) * (1.f/(DEG*DOUT));
}

__global__ void smtp_reduce(const float* __restrict__ partial, int B, float* __restrict__ out)
{
  __shared__ float sRed[4];
  const int tid = threadIdx.x;
  float s = 0.f;
  for (int i = tid; i < B; i += NTHREADS) s += partial[i];
  s = wred(s);
  if ((tid & 63) == 0) sRed[tid>>6] = s;
  __syncthreads();
  if (tid == 0) out[0] = (sRed[0]+sRed[1]+sRed[2]+sRed[3]) / (float)B;
}

extern "C" void kernel_launch(void* const* d_in, const int* in_sizes, int n_in,
                              void* d_out, int out_size, void* d_ws, size_t ws_size,
                              hipStream_t stream) {
  const float* H        = (const float*)d_in[0];
  const int*   edge     = (const int*)d_in[1];
  const int*   centers  = (const int*)d_in[2];
  const float* target   = (const float*)d_in[3];
  // d_in[4] = max_deg scalar (compile-time DEG=32)
  const float* ln_in_w  = (const float*)d_in[5];
  const float* ln1_w    = (const float*)d_in[6];
  const float* ln2_w    = (const float*)d_in[7];
  const float* w_qkv    = (const float*)d_in[8];
  const float* b_qkv    = (const float*)d_in[9];
  const float* w_o      = (const float*)d_in[10];
  const float* b_o      = (const float*)d_in[11];
  const float* w_gate   = (const float*)d_in[12];
  const float* w_up     = (const float*)d_in[13];
  const float* w_down   = (const float*)d_in[14];
  const float* w_head   = (const float*)d_in[15];
  const float* b_head   = (const float*)d_in[16];

  const int B = in_sizes[2];
  const int E = in_sizes[1] / 2;
  const int* dstE = edge + E;          // edge_index row 1
  float* partial = (float*)d_ws;       // B floats of scratch, fully rewritten every call

  smtp_center<<<B, NTHREADS, 0, stream>>>(H, dstE, centers, target, ln_in_w, ln1_w, ln2_w,
      w_qkv, b_qkv, w_o, b_o, w_gate, w_up, w_down, w_head, b_head, partial);
  smtp_reduce<<<1, NTHREADS, 0, stream>>>(partial, B, (float*)d_out);
}

// Round 2
// 1758.282 us; speedup vs baseline: 18.9256x; 18.9256x over previous
//
#include <hip/hip_runtime.h>

#define DM 256
#define NH 4
#define HD 64
#define DEG 32
#define LQ 33
#define DOUT 128
#define NTHREADS 256

typedef __attribute__((ext_vector_type(8))) short bf8v;   // 8 bf16 = 4 VGPRs (MFMA A/B frag)
typedef __attribute__((ext_vector_type(4))) float f4v;    // MFMA C/D frag

// bf16 helpers
__device__ __forceinline__ float blo(unsigned int u){ union{unsigned int i;float f;}v; v.i=u<<16; return v.f; }
__device__ __forceinline__ float bhi(unsigned int u){ union{unsigned int i;float f;}v; v.i=u&0xFFFF0000u; return v.f; }
__device__ __forceinline__ float b2f(unsigned short u){ union{unsigned int i;float f;}v; v.i=((unsigned int)u)<<16; return v.f; }
__device__ __forceinline__ unsigned short f2b(float f){
  union{float f;unsigned int i;}v; v.f=f;
  unsigned int r=v.i+0x7FFFu+((v.i>>16)&1u);
  return (unsigned short)(r>>16);
}
__device__ __forceinline__ float wred(float x){
  #pragma unroll
  for (int o=32;o>=1;o>>=1) x += __shfl_xor(x,o,64);
  return x;
}
__device__ __forceinline__ float wmax(float x){
  #pragma unroll
  for (int o=32;o>=1;o>>=1) x = fmaxf(x,__shfl_xor(x,o,64));
  return x;
}

// XOR swizzle for [48][256] bf16 LDS tiles read as ds_read_b128 A-fragments:
// chunk(16B) index ^= row&7 -> lanes 0-15 (same k-chunk, rows 0-15) land on 8
// distinct 16B slots = 2-way (free). Bijective within each row.
__device__ __forceinline__ int swz(int r, int c){ return r*DM + (((c>>3) ^ (r&7))<<3) + (c&7); }
// same for [48][64] AO tile (8 chunks/row)
__device__ __forceinline__ int swzAO(int r, int c){ return r*HD + (((c>>3) ^ (r&7))<<3) + (c&7); }

// B-fragment: lane needs W[row][e .. e+7] as bf16 (e = k*32 + (lane>>4)*8)
template<bool BF>
__device__ __forceinline__ bf8v wfrag(const float* Wf, const unsigned short* Wb, int row, int e){
  if constexpr (BF) {
    return *(const bf8v*)(Wb + (size_t)row*DM + e);
  } else {
    const float* p = Wf + (size_t)row*DM + e;
    const float4 a = *(const float4*)p;
    const float4 b = *(const float4*)(p+4);
    bf8v r;
    r[0]=(short)(__float_as_uint(a.x)>>16); r[1]=(short)(__float_as_uint(a.y)>>16);
    r[2]=(short)(__float_as_uint(a.z)>>16); r[3]=(short)(__float_as_uint(a.w)>>16);
    r[4]=(short)(__float_as_uint(b.x)>>16); r[5]=(short)(__float_as_uint(b.y)>>16);
    r[6]=(short)(__float_as_uint(b.z)>>16); r[7]=(short)(__float_as_uint(b.w)>>16);
    return r;
  }
}

__device__ __forceinline__ f4v mfma16(bf8v a, bf8v b, f4v c){
  return __builtin_amdgcn_mfma_f32_16x16x32_bf16(a, b, c, 0, 0, 0);
}

// U region layout (ushort indices): Q[0,3072) stride64 | K[3072,6528) stride72 | V[6528,9600) stride64 | AO[9600,12672) swizzled
// After attention: sMid = U[0,12288) as swizzled [48][256]
#define U_Q  0
#define U_K  3072
#define U_V  6528
#define U_AO 9600

template<bool WBF16>
__global__ __launch_bounds__(NTHREADS, 2) void smtp_center(
    const float* __restrict__ H,
    const int* __restrict__ dstE,
    const int* __restrict__ centers,
    const float* __restrict__ target,
    const float* __restrict__ ln_in_w,
    const float* __restrict__ ln1_w,
    const float* __restrict__ ln2_w,
    const float* __restrict__ w_qkv,
    const float* __restrict__ b_qkv,
    const float* __restrict__ w_o,
    const float* __restrict__ b_o,
    const float* __restrict__ w_gate,
    const float* __restrict__ w_up,
    const float* __restrict__ w_down,
    const float* __restrict__ w_head,
    const float* __restrict__ b_head,
    const unsigned short* __restrict__ wb,   // bf16 weights in ws (valid iff WBF16)
    float* __restrict__ partial)
{
  __shared__ __align__(16) unsigned short sX[48*DM];   // residual, plain layout
  __shared__ __align__(16) unsigned short sN[48*DM];   // xn / xn2 / Z, swizzled
  __shared__ __align__(16) unsigned short U[12672];
  __shared__ float sAttn[4*34];
  __shared__ int sIdx[48];
  __shared__ float sRed[4];

  const unsigned short* wbQKV = wb;
  const unsigned short* wbO   = wb + 196608;
  const unsigned short* wbG   = wb + 262144;
  const unsigned short* wbU   = wb + 327680;
  const unsigned short* wbD   = wb + 393216;
  const unsigned short* wbH   = wb + 458752;

  const int tid  = threadIdx.x;
  const int lane = tid & 63;
  const int wave = tid >> 6;
  const int bid  = blockIdx.x;
  const int l15  = lane & 15;
  const int l16  = (lane >> 4) * 8;     // k sub-offset of this lane's fragment
  const int rsub = (lane >> 4) * 4;     // C-tile row base for this lane

  // P0: star indices (CSR collapses: exactly DEG sorted out-edges per node)
  if (tid < LQ) {
    int ctr = centers[bid];
    sIdx[tid] = (tid == 0) ? ctr : dstE[(size_t)ctr*DEG + (tid-1)];
  }
  __syncthreads();

  // P1: gather + rmsnorm(ln_in) -> sX, rmsnorm(ln1) -> sN(swz); zero pads
  for (int r = wave; r < LQ; r += 4) {
    const float4 x4 = ((const float4*)(H + (size_t)sIdx[r]*DM))[lane];
    float ss = x4.x*x4.x + x4.y*x4.y + x4.z*x4.z + x4.w*x4.w;
    ss = wred(ss);
    const float rs = rsqrtf(ss*(1.f/DM) + 1e-6f);
    const float4 wi = ((const float4*)ln_in_w)[lane];
    const float xv0 = x4.x*rs*wi.x, xv1 = x4.y*rs*wi.y, xv2 = x4.z*rs*wi.z, xv3 = x4.w*rs*wi.w;
    ushort4 xb; xb.x=f2b(xv0); xb.y=f2b(xv1); xb.z=f2b(xv2); xb.w=f2b(xv3);
    ((ushort4*)(sX + r*DM))[lane] = xb;
    float s2 = xv0*xv0 + xv1*xv1 + xv2*xv2 + xv3*xv3;
    s2 = wred(s2);
    const float rs2 = rsqrtf(s2*(1.f/DM) + 1e-6f);
    const float4 w1 = ((const float4*)ln1_w)[lane];
    ushort4 yb; yb.x=f2b(xv0*rs2*w1.x); yb.y=f2b(xv1*rs2*w1.y); yb.z=f2b(xv2*rs2*w1.z); yb.w=f2b(xv3*rs2*w1.w);
    *(ushort4*)(sN + swz(r, lane*4)) = yb;
  }
  {
    ushort4 z4; z4.x=0; z4.y=0; z4.z=0; z4.w=0;
    for (int r = LQ + wave; r < 48; r += 4) {
      ((ushort4*)(sX + r*DM))[lane] = z4;
      ((ushort4*)(sN + r*DM))[lane] = z4;   // zeros are swizzle-invariant
      U[U_AO + r*HD + lane] = 0;            // AO pad rows stay zero all heads
    }
  }
  __syncthreads();

  // P2: per-head {QKV mfma-GEMM, VALU attention, WO mfma-GEMM accum into sX}
  for (int h = 0; h < NH; ++h) {
    // QKV GEMM: M=48(3 tiles) x N=192 (Q|K|V of head h), K=256. 3 N-tiles/wave.
    for (int t3 = 0; t3 < 3; ++t3) {
      const int t = wave*3 + t3;
      const int col = t*16 + l15;          // 0..191
      const int sect = t >> 2;             // 0=Q 1=K 2=V
      const int c = col & 63;
      const int wrow = sect*DM + h*HD + c;
      const float bias = b_qkv[wrow];
      f4v acc[3];
      acc[0] = (f4v){bias,bias,bias,bias}; acc[1] = acc[0]; acc[2] = acc[0];
      #pragma unroll
      for (int k = 0; k < 8; ++k) {
        const bf8v b = wfrag<WBF16>(w_qkv, wbQKV, wrow, k*32 + l16);
        #pragma unroll
        for (int m = 0; m < 3; ++m) {
          const bf8v a = *(const bf8v*)(sN + swz(m*16 + l15, k*32 + l16));
          acc[m] = mfma16(a, b, acc[m]);
        }
      }
      unsigned short* dstb = (sect==0) ? (U+U_Q) : (sect==1) ? (U+U_K) : (U+U_V);
      const int stride = (sect==1) ? 72 : 64;
      #pragma unroll
      for (int m = 0; m < 3; ++m)
        #pragma unroll
        for (int j = 0; j < 4; ++j)
          dstb[(m*16 + rsub + j)*stride + c] = f2b(acc[m][j]);
    }
    __syncthreads();

    // attention (VALU): wave per query row; lane=key for scores, lane=col for PV
    for (int qr = wave; qr < LQ; qr += 4) {
      float s = -INFINITY;
      if (lane < LQ) {
        const uint4* Qp = (const uint4*)(U + U_Q + qr*HD);
        const uint4* Kp = (const uint4*)(U + U_K + lane*72);
        float d = 0.f;
        #pragma unroll
        for (int j = 0; j < HD/8; ++j) {
          const uint4 q = Qp[j], k = Kp[j];
          d += blo(q.x)*blo(k.x) + bhi(q.x)*bhi(k.x);
          d += blo(q.y)*blo(k.y) + bhi(q.y)*bhi(k.y);
          d += blo(q.z)*blo(k.z) + bhi(q.z)*bhi(k.z);
          d += blo(q.w)*blo(k.w) + bhi(q.w)*bhi(k.w);
        }
        s = d * 0.125f;
      }
      const float mx = wmax(s);
      const float e = (lane < LQ) ? __expf(s - mx) : 0.f;
      const float den = wred(e);
      if (lane < LQ) sAttn[wave*34 + lane] = e / den;
      float acc = 0.f;
      #pragma unroll
      for (int k = 0; k < LQ; ++k)
        acc += sAttn[wave*34 + k] * b2f(U[U_V + k*HD + lane]);
      U[U_AO + swzAO(qr, lane)] = f2b(acc);
    }
    __syncthreads();

    // WO GEMM: X += AO_h @ w_o[:, h*64:(h+1)*64]^T (+b_o once). M=48 x N=256, K=64.
    for (int t4 = 0; t4 < 4; ++t4) {
      const int col = (wave*4 + t4)*16 + l15;    // 0..255
      const float bo = (h==0) ? b_o[col] : 0.f;
      f4v acc[3];
      #pragma unroll
      for (int m = 0; m < 3; ++m) {
        #pragma unroll
        for (int j = 0; j < 4; ++j)
          acc[m][j] = b2f(sX[(m*16 + rsub + j)*DM + col]) + bo;
      }
      #pragma unroll
      for (int k = 0; k < 2; ++k) {
        const bf8v b = wfrag<WBF16>(w_o, wbO, col, h*HD + k*32 + l16);
        #pragma unroll
        for (int m = 0; m < 3; ++m) {
          const bf8v a = *(const bf8v*)(U + U_AO + swzAO(m*16 + l15, k*32 + l16));
          acc[m] = mfma16(a, b, acc[m]);
        }
      }
      #pragma unroll
      for (int m = 0; m < 3; ++m)
        #pragma unroll
        for (int j = 0; j < 4; ++j)
          sX[(m*16 + rsub + j)*DM + col] = f2b(acc[m][j]);
    }
    __syncthreads();
  }

  // P3: xn2 = rmsnorm(X, ln2) -> sN(swz)
  for (int r = wave; r < LQ; r += 4) {
    const ushort4 xb = ((const ushort4*)(sX + r*DM))[lane];
    const float x0 = b2f(xb.x), x1 = b2f(xb.y), x2 = b2f(xb.z), x3 = b2f(xb.w);
    float ss = x0*x0 + x1*x1 + x2*x2 + x3*x3;
    ss = wred(ss);
    const float rs = rsqrtf(ss*(1.f/DM) + 1e-6f);
    const float4 w2 = ((const float4*)ln2_w)[lane];
    ushort4 yb; yb.x=f2b(x0*rs*w2.x); yb.y=f2b(x1*rs*w2.y); yb.z=f2b(x2*rs*w2.z); yb.w=f2b(x3*rs*w2.w);
    *(ushort4*)(sN + swz(r, lane*4)) = yb;
  }
  __syncthreads();

  // P4: gate/up GEMM -> mid = silu(g)*u -> sMid (U region, swizzled)
  for (int t4 = 0; t4 < 4; ++t4) {
    const int col = (wave*4 + t4)*16 + l15;
    f4v aG[3], aU[3];
    #pragma unroll
    for (int m = 0; m < 3; ++m) { aG[m] = (f4v){0.f,0.f,0.f,0.f}; aU[m] = aG[m]; }
    #pragma unroll
    for (int k = 0; k < 8; ++k) {
      const bf8v bg = wfrag<WBF16>(w_gate, wbG, col, k*32 + l16);
      const bf8v bu = wfrag<WBF16>(w_up,   wbU, col, k*32 + l16);
      #pragma unroll
      for (int m = 0; m < 3; ++m) {
        const bf8v a = *(const bf8v*)(sN + swz(m*16 + l15, k*32 + l16));
        aG[m] = mfma16(a, bg, aG[m]);
        aU[m] = mfma16(a, bu, aU[m]);
      }
    }
    #pragma unroll
    for (int m = 0; m < 3; ++m)
      #pragma unroll
      for (int j = 0; j < 4; ++j) {
        const float g = aG[m][j];
        const float v = (g / (1.f + __expf(-g))) * aU[m][j];
        U[swz(m*16 + rsub + j, col)] = f2b(v);
      }
  }
  __syncthreads();

  // P5: Z = X + mid @ w_down^T -> sN(swz)
  for (int t4 = 0; t4 < 4; ++t4) {
    const int col = (wave*4 + t4)*16 + l15;
    f4v acc[3];
    #pragma unroll
    for (int m = 0; m < 3; ++m) {
      #pragma unroll
      for (int j = 0; j < 4; ++j)
        acc[m][j] = b2f(sX[(m*16 + rsub + j)*DM + col]);
    }
    #pragma unroll
    for (int k = 0; k < 8; ++k) {
      const bf8v b = wfrag<WBF16>(w_down, wbD, col, k*32 + l16);
      #pragma unroll
      for (int m = 0; m < 3; ++m) {
        const bf8v a = *(const bf8v*)(U + swz(m*16 + l15, k*32 + l16));
        acc[m] = mfma16(a, b, acc[m]);
      }
    }
    #pragma unroll
    for (int m = 0; m < 3; ++m)
      #pragma unroll
      for (int j = 0; j < 4; ++j)
        sN[swz(m*16 + rsub + j, col)] = f2b(acc[m][j]);
  }
  __syncthreads();

  // P6: head GEMM on rows 1..32 (M=2 tiles exactly) + MSE vs gathered targets
  float lsum = 0.f;
  for (int t2 = 0; t2 < 2; ++t2) {
    const int col = (wave*2 + t2)*16 + l15;   // 0..127
    const float bh = b_head[col];
    f4v acc[2];
    acc[0] = (f4v){bh,bh,bh,bh}; acc[1] = acc[0];
    #pragma unroll
    for (int k = 0; k < 8; ++k) {
      const bf8v b = wfrag<WBF16>(w_head, wbH, col, k*32 + l16);
      #pragma unroll
      for (int m = 0; m < 2; ++m) {
        const bf8v a = *(const bf8v*)(sN + swz(1 + m*16 + l15, k*32 + l16));
        acc[m] = mfma16(a, b, acc[m]);
      }
    }
    #pragma unroll
    for (int m = 0; m < 2; ++m)
      #pragma unroll
      for (int j = 0; j < 4; ++j) {
        const int row = 1 + m*16 + rsub + j;          // 1..32
        const float tv = target[(size_t)sIdx[row]*DOUT + col];
        const float d = acc[m][j] - tv;
        lsum += d*d;
      }
  }
  lsum = wred(lsum);
  if (lane == 0) sRed[wave] = lsum;
  __syncthreads();
  if (tid == 0)
    partial[bid] = (sRed[0]+sRed[1]+sRed[2]+sRed[3]) * (1.f/(DEG*DOUT));
}

// one-time (per launch) f32 -> bf16 weight conversion into d_ws
__global__ void cvt_w(const float* __restrict__ qkv, const float* __restrict__ o,
                      const float* __restrict__ g, const float* __restrict__ u,
                      const float* __restrict__ dn, const float* __restrict__ hd,
                      unsigned short* __restrict__ out)
{
  const int i = blockIdx.x*NTHREADS + threadIdx.x;
  const int e = i*2;
  if (e >= 491520) return;
  const float* src; int off;
  if      (e < 196608){ src=qkv; off=e; }
  else if (e < 262144){ src=o;  off=e-196608; }
  else if (e < 327680){ src=g;  off=e-262144; }
  else if (e < 393216){ src=u;  off=e-327680; }
  else if (e < 458752){ src=dn; off=e-393216; }
  else                { src=hd; off=e-458752; }
  const float2 v = *(const float2*)(src + off);
  const unsigned int pk = (unsigned int)f2b(v.x) | ((unsigned int)f2b(v.y) << 16);
  *(unsigned int*)(out + e) = pk;
}

__global__ void smtp_reduce(const float* __restrict__ partial, int B, float* __restrict__ out)
{
  __shared__ float sRed[4];
  const int tid = threadIdx.x;
  float s = 0.f;
  for (int i = tid; i < B; i += NTHREADS) s += partial[i];
  s = wred(s);
  if ((tid & 63) == 0) sRed[tid>>6] = s;
  __syncthreads();
  if (tid == 0) out[0] = (sRed[0]+sRed[1]+sRed[2]+sRed[3]) / (float)B;
}

extern "C" void kernel_launch(void* const* d_in, const int* in_sizes, int n_in,
                              void* d_out, int out_size, void* d_ws, size_t ws_size,
                              hipStream_t stream) {
  const float* H        = (const float*)d_in[0];
  const int*   edge     = (const int*)d_in[1];
  const int*   centers  = (const int*)d_in[2];
  const float* target   = (const float*)d_in[3];
  // d_in[4] = max_deg scalar (compile-time DEG=32)
  const float* ln_in_w  = (const float*)d_in[5];
  const float* ln1_w    = (const float*)d_in[6];
  const float* ln2_w    = (const float*)d_in[7];
  const float* w_qkv    = (const float*)d_in[8];
  const float* b_qkv    = (const float*)d_in[9];
  const float* w_o      = (const float*)d_in[10];
  const float* b_o      = (const float*)d_in[11];
  const float* w_gate   = (const float*)d_in[12];
  const float* w_up     = (const float*)d_in[13];
  const float* w_down   = (const float*)d_in[14];
  const float* w_head   = (const float*)d_in[15];
  const float* b_head   = (const float*)d_in[16];

  const int B = in_sizes[2];
  const int E = in_sizes[1] / 2;
  const int* dstE = edge + E;

  const size_t WB_ELEMS = 491520;               // bf16 weight elements
  const size_t NEED = WB_ELEMS*2 + (size_t)B*4; // weights + partial
  const bool useBf = (ws_size >= NEED);

  if (useBf) {
    unsigned short* wb = (unsigned short*)d_ws;
    float* partial = (float*)((char*)d_ws + WB_ELEMS*2);
    cvt_w<<<960, NTHREADS, 0, stream>>>(w_qkv, w_o, w_gate, w_up, w_down, w_head, wb);
    smtp_center<true><<<B, NTHREADS, 0, stream>>>(H, dstE, centers, target, ln_in_w, ln1_w, ln2_w,
        w_qkv, b_qkv, w_o, b_o, w_gate, w_up, w_down, w_head, b_head, wb, partial);
    smtp_reduce<<<1, NTHREADS, 0, stream>>>(partial, B, (float*)d_out);
  } else {
    float* partial = (float*)d_ws;
    smtp_center<false><<<B, NTHREADS, 0, stream>>>(H, dstE, centers, target, ln_in_w, ln1_w, ln2_w,
        w_qkv, b_qkv, w_o, b_o, w_gate, w_up, w_down, w_head, b_head, (const unsigned short*)d_ws, partial);
    smtp_reduce<<<1, NTHREADS, 0, stream>>>(partial, B, (float*)d_out);
  }
}

// Round 3
// 1219.010 us; speedup vs baseline: 27.2980x; 1.4424x over previous
//
#include <hip/hip_runtime.h>

#define DM 256
#define NH 4
#define HD 64
#define DEG 32
#define LQ 33
#define DOUT 128
#define NTHREADS 256
#define XS 268   // sX row stride (u16): 4-row groups hit banks 0/24/16/8 -> conflict-free
#define QS 72    // Q/K row stride (u16): 2-way (free)

typedef __attribute__((ext_vector_type(8))) short bf8v;   // 8 bf16 = 4 VGPRs (MFMA A/B frag)
typedef __attribute__((ext_vector_type(4))) float f4v;    // MFMA C/D frag

__device__ __forceinline__ float b2f(unsigned short u){ union{unsigned int i;float f;}v; v.i=((unsigned int)u)<<16; return v.f; }
__device__ __forceinline__ unsigned short f2b(float f){
  union{float f;unsigned int i;}v; v.f=f;
  unsigned int r=v.i+0x7FFFu+((v.i>>16)&1u);
  return (unsigned short)(r>>16);
}
__device__ __forceinline__ float wred(float x){
  #pragma unroll
  for (int o=32;o>=1;o>>=1) x += __shfl_xor(x,o,64);
  return x;
}

// XOR swizzle for [R][256] bf16 LDS tiles read as ds_read_b128 A-fragments
__device__ __forceinline__ int swz(int r, int c){ return r*DM + (((c>>3) ^ (r&7))<<3) + (c&7); }
// XOR swizzle for [R][64] bf16 tiles (P, VT, AO)
__device__ __forceinline__ int swzV(int r, int c){ return r*HD + (((c>>3) ^ (r&7))<<3) + (c&7); }

// B-fragment: lane needs W[row][e .. e+7] as bf16
template<bool BF>
__device__ __forceinline__ bf8v wfrag(const float* Wf, const unsigned short* Wb, int row, int e){
  if constexpr (BF) {
    return *(const bf8v*)(Wb + (size_t)row*DM + e);
  } else {
    const float* p = Wf + (size_t)row*DM + e;
    const float4 a = *(const float4*)p;
    const float4 b = *(const float4*)(p+4);
    bf8v r;
    r[0]=(short)(__float_as_uint(a.x)>>16); r[1]=(short)(__float_as_uint(a.y)>>16);
    r[2]=(short)(__float_as_uint(a.z)>>16); r[3]=(short)(__float_as_uint(a.w)>>16);
    r[4]=(short)(__float_as_uint(b.x)>>16); r[5]=(short)(__float_as_uint(b.y)>>16);
    r[6]=(short)(__float_as_uint(b.z)>>16); r[7]=(short)(__float_as_uint(b.w)>>16);
    return r;
  }
}

__device__ __forceinline__ f4v mfma16(bf8v a, bf8v b, f4v c){
  return __builtin_amdgcn_mfma_f32_16x16x32_bf16(a, b, c, 0, 0, 0);
}

// U region (u16 indices). Concurrent sets:
//  {Q,K,VT} (QKV+scores) -> {P(=Q),VT,AO(=K)} (PV) -> {AO} (WO) -> sMid[48][256] (MLP)
#define U_Q  0      // [48][72]
#define U_K  3456   // [48][72]
#define U_VT 6912   // [64][64] swizzled, VT[d][key]
#define U_P  0      // [48][64] swizzled (overlays Q)
#define U_AO 3456   // [48][64] swizzled (overlays K)
#define U_SZ 12288  // sMid [48][256] swizzled reuses whole region

template<bool WBF16>
__global__ __launch_bounds__(NTHREADS, 2) void smtp_center(
    const float* __restrict__ H,
    const int* __restrict__ dstE,
    const int* __restrict__ centers,
    const float* __restrict__ target,
    const float* __restrict__ ln_in_w,
    const float* __restrict__ ln1_w,
    const float* __restrict__ ln2_w,
    const float* __restrict__ w_qkv,
    const float* __restrict__ b_qkv,
    const float* __restrict__ w_o,
    const float* __restrict__ b_o,
    const float* __restrict__ w_gate,
    const float* __restrict__ w_up,
    const float* __restrict__ w_down,
    const float* __restrict__ w_head,
    const float* __restrict__ b_head,
    const unsigned short* __restrict__ wb,
    float* __restrict__ partial)
{
  __shared__ __align__(16) unsigned short sX[48*XS];   // residual, padded stride
  __shared__ __align__(16) unsigned short sN[48*DM];   // xn / xn2 / Z, swizzled
  __shared__ __align__(16) unsigned short U[U_SZ];
  __shared__ int sIdx[48];
  __shared__ float sRed[4];

  const unsigned short* wbQKV = wb;
  const unsigned short* wbO   = wb + 196608;
  const unsigned short* wbG   = wb + 262144;
  const unsigned short* wbU   = wb + 327680;
  const unsigned short* wbD   = wb + 393216;
  const unsigned short* wbH   = wb + 458752;

  const int tid  = threadIdx.x;
  const int lane = tid & 63;
  const int wave = tid >> 6;
  const int bid  = blockIdx.x;
  const int l15  = lane & 15;
  const int l16  = (lane >> 4) * 8;     // k sub-offset of this lane's fragment
  const int rsub = (lane >> 4) * 4;     // C-tile row base for this lane

  // P0: star indices
  if (tid < LQ) {
    int ctr = centers[bid];
    sIdx[tid] = (tid == 0) ? ctr : dstE[(size_t)ctr*DEG + (tid-1)];
  }
  __syncthreads();

  // P1: gather + rmsnorm(ln_in) -> sX, rmsnorm(ln1) -> sN(swz); zero pads; zero VT keys 48..63
  for (int r = wave; r < LQ; r += 4) {
    const float4 x4 = ((const float4*)(H + (size_t)sIdx[r]*DM))[lane];
    float ss = x4.x*x4.x + x4.y*x4.y + x4.z*x4.z + x4.w*x4.w;
    ss = wred(ss);
    const float rs = rsqrtf(ss*(1.f/DM) + 1e-6f);
    const float4 wi = ((const float4*)ln_in_w)[lane];
    const float xv0 = x4.x*rs*wi.x, xv1 = x4.y*rs*wi.y, xv2 = x4.z*rs*wi.z, xv3 = x4.w*rs*wi.w;
    ushort4 xb; xb.x=f2b(xv0); xb.y=f2b(xv1); xb.z=f2b(xv2); xb.w=f2b(xv3);
    ((ushort4*)(sX + r*XS))[lane] = xb;
    float s2 = xv0*xv0 + xv1*xv1 + xv2*xv2 + xv3*xv3;
    s2 = wred(s2);
    const float rs2 = rsqrtf(s2*(1.f/DM) + 1e-6f);
    const float4 w1 = ((const float4*)ln1_w)[lane];
    ushort4 yb; yb.x=f2b(xv0*rs2*w1.x); yb.y=f2b(xv1*rs2*w1.y); yb.z=f2b(xv2*rs2*w1.z); yb.w=f2b(xv3*rs2*w1.w);
    *(ushort4*)(sN + swz(r, lane*4)) = yb;
  }
  {
    ushort4 z4; z4.x=0; z4.y=0; z4.z=0; z4.w=0;
    for (int r = LQ + wave; r < 48; r += 4) {
      ((ushort4*)(sX + r*XS))[lane] = z4;
      ((ushort4*)(sN + r*DM))[lane] = z4;   // zeros are swizzle-invariant
    }
    if (tid < 128) {                        // VT keys 48..63 (chunks 6,7) = 0, once
      const int d = tid >> 1, ch = 6 + (tid & 1);
      *(uint4*)&U[U_VT + d*HD + ((ch ^ (d&7))<<3)] = make_uint4(0,0,0,0);
    }
  }
  __syncthreads();

  // P2: per head: {QKV mfma, scores mfma, in-reg softmax, PV mfma, WO mfma}
  for (int h = 0; h < NH; ++h) {
    // 2a QKV: M=48 x N=192 (Q|K|V of head h), K=256. 3 N-tiles per wave.
    for (int t3 = 0; t3 < 3; ++t3) {
      const int t = wave*3 + t3;
      const int col = t*16 + l15;
      const int sect = t >> 2;             // 0=Q 1=K 2=V
      const int c = col & 63;
      const int wrow = sect*DM + h*HD + c;
      const float bias = b_qkv[wrow];
      f4v acc[3];
      acc[0] = (f4v){bias,bias,bias,bias}; acc[1] = acc[0]; acc[2] = acc[0];
      #pragma unroll
      for (int k = 0; k < 8; ++k) {
        const bf8v b = wfrag<WBF16>(w_qkv, wbQKV, wrow, k*32 + l16);
        #pragma unroll
        for (int m = 0; m < 3; ++m) {
          const bf8v a = *(const bf8v*)(sN + swz(m*16 + l15, k*32 + l16));
          acc[m] = mfma16(a, b, acc[m]);
        }
      }
      if (sect == 2) {                     // V -> VT[d][key]
        #pragma unroll
        for (int m = 0; m < 3; ++m)
          #pragma unroll
          for (int j = 0; j < 4; ++j)
            U[U_VT + swzV(c, m*16 + rsub + j)] = f2b(acc[m][j]);
      } else {
        unsigned short* dstb = U + (sect ? U_K : U_Q);
        #pragma unroll
        for (int m = 0; m < 3; ++m)
          #pragma unroll
          for (int j = 0; j < 4; ++j)
            dstb[(m*16 + rsub + j)*QS + c] = f2b(acc[m][j]);
      }
    }
    __syncthreads();

    // 2b scores: wave w (<3) computes S rows [w*16, w*16+16) x all 48 keys, K=64
    f4v s3[3];
    s3[0] = (f4v){0.f,0.f,0.f,0.f}; s3[1] = s3[0]; s3[2] = s3[0];
    if (wave < 3) {
      #pragma unroll
      for (int kk = 0; kk < 2; ++kk) {
        const bf8v a = *(const bf8v*)(U + U_Q + (wave*16 + l15)*QS + kk*32 + l16);
        #pragma unroll
        for (int nk = 0; nk < 3; ++nk) {
          const bf8v bb = *(const bf8v*)(U + U_K + (nk*16 + l15)*QS + kk*32 + l16);
          s3[nk] = mfma16(a, bb, s3[nk]);
        }
      }
    }
    __syncthreads();   // Q,K dead; P may now overwrite Q region

    // 2c softmax (waves 0-2, in-register) + P pad-key zeroing (wave 3)
    if (wave == 3) {
      for (int i = lane; i < 96; i += 64) {      // P keys 48..63 (chunks 6,7) = 0
        const int r = i >> 1, ch = 6 + (i & 1);
        *(uint4*)&U[U_P + r*HD + ((ch ^ (r&7))<<3)] = make_uint4(0,0,0,0);
      }
    } else {
      #pragma unroll
      for (int j = 0; j < 4; ++j) {
        const float v0 = s3[0][j]*0.125f;
        const float v1 = s3[1][j]*0.125f;
        const float v2 = (l15 >= 1) ? -INFINITY : s3[2][j]*0.125f;  // keys 33..47 masked
        float mx = fmaxf(fmaxf(v0, v1), v2);
        mx = fmaxf(mx, __shfl_xor(mx, 1, 64));
        mx = fmaxf(mx, __shfl_xor(mx, 2, 64));
        mx = fmaxf(mx, __shfl_xor(mx, 4, 64));
        mx = fmaxf(mx, __shfl_xor(mx, 8, 64));
        const float e0 = __expf(v0 - mx), e1 = __expf(v1 - mx), e2 = __expf(v2 - mx);
        float den = e0 + e1 + e2;
        den += __shfl_xor(den, 1, 64);
        den += __shfl_xor(den, 2, 64);
        den += __shfl_xor(den, 4, 64);
        den += __shfl_xor(den, 8, 64);
        const float rn = 1.f / den;
        const int row = wave*16 + rsub + j;
        U[U_P + swzV(row, 0*16 + l15)] = f2b(e0 * rn);
        U[U_P + swzV(row, 1*16 + l15)] = f2b(e1 * rn);
        U[U_P + swzV(row, 2*16 + l15)] = f2b(e2 * rn);
      }
    }
    __syncthreads();

    // 2d PV: O[q][d] = P @ V; wave = d-tile. K = 64 (keys 33..63 have P=0)
    {
      f4v o4[3];
      o4[0] = (f4v){0.f,0.f,0.f,0.f}; o4[1] = o4[0]; o4[2] = o4[0];
      #pragma unroll
      for (int kk = 0; kk < 2; ++kk) {
        const bf8v bb = *(const bf8v*)(U + U_VT + swzV(wave*16 + l15, kk*32 + l16));
        #pragma unroll
        for (int mq = 0; mq < 3; ++mq) {
          const bf8v a = *(const bf8v*)(U + U_P + swzV(mq*16 + l15, kk*32 + l16));
          o4[mq] = mfma16(a, bb, o4[mq]);
        }
      }
      #pragma unroll
      for (int mq = 0; mq < 3; ++mq)
        #pragma unroll
        for (int j = 0; j < 4; ++j)
          U[U_AO + swzV(mq*16 + rsub + j, wave*16 + l15)] = f2b(o4[mq][j]);
    }
    __syncthreads();

    // 2e WO: X += AO_h @ w_o[:, h*64:(h+1)*64]^T (+b_o once). M=48 x N=256, K=64.
    for (int t4 = 0; t4 < 4; ++t4) {
      const int col = (wave*4 + t4)*16 + l15;
      const float bo = (h==0) ? b_o[col] : 0.f;
      f4v acc[3];
      #pragma unroll
      for (int m = 0; m < 3; ++m) {
        #pragma unroll
        for (int j = 0; j < 4; ++j)
          acc[m][j] = b2f(sX[(m*16 + rsub + j)*XS + col]) + bo;
      }
      #pragma unroll
      for (int k = 0; k < 2; ++k) {
        const bf8v b = wfrag<WBF16>(w_o, wbO, col, h*HD + k*32 + l16);
        #pragma unroll
        for (int m = 0; m < 3; ++m) {
          const bf8v a = *(const bf8v*)(U + U_AO + swzV(m*16 + l15, k*32 + l16));
          acc[m] = mfma16(a, b, acc[m]);
        }
      }
      #pragma unroll
      for (int m = 0; m < 3; ++m)
        #pragma unroll
        for (int j = 0; j < 4; ++j)
          sX[(m*16 + rsub + j)*XS + col] = f2b(acc[m][j]);
    }
    __syncthreads();
  }

  // P3: xn2 = rmsnorm(X, ln2) -> sN(swz)
  for (int r = wave; r < LQ; r += 4) {
    const ushort4 xb = ((const ushort4*)(sX + r*XS))[lane];
    const float x0 = b2f(xb.x), x1 = b2f(xb.y), x2 = b2f(xb.z), x3 = b2f(xb.w);
    float ss = x0*x0 + x1*x1 + x2*x2 + x3*x3;
    ss = wred(ss);
    const float rs = rsqrtf(ss*(1.f/DM) + 1e-6f);
    const float4 w2 = ((const float4*)ln2_w)[lane];
    ushort4 yb; yb.x=f2b(x0*rs*w2.x); yb.y=f2b(x1*rs*w2.y); yb.z=f2b(x2*rs*w2.z); yb.w=f2b(x3*rs*w2.w);
    *(ushort4*)(sN + swz(r, lane*4)) = yb;
  }
  __syncthreads();

  // P4: gate/up GEMM -> mid = silu(g)*u -> U (swizzled [48][256])
  for (int t4 = 0; t4 < 4; ++t4) {
    const int col = (wave*4 + t4)*16 + l15;
    f4v aG[3], aU[3];
    #pragma unroll
    for (int m = 0; m < 3; ++m) { aG[m] = (f4v){0.f,0.f,0.f,0.f}; aU[m] = aG[m]; }
    #pragma unroll
    for (int k = 0; k < 8; ++k) {
      const bf8v bg = wfrag<WBF16>(w_gate, wbG, col, k*32 + l16);
      const bf8v bu = wfrag<WBF16>(w_up,   wbU, col, k*32 + l16);
      #pragma unroll
      for (int m = 0; m < 3; ++m) {
        const bf8v a = *(const bf8v*)(sN + swz(m*16 + l15, k*32 + l16));
        aG[m] = mfma16(a, bg, aG[m]);
        aU[m] = mfma16(a, bu, aU[m]);
      }
    }
    #pragma unroll
    for (int m = 0; m < 3; ++m)
      #pragma unroll
      for (int j = 0; j < 4; ++j) {
        const float g = aG[m][j];
        const float v = (g / (1.f + __expf(-g))) * aU[m][j];
        U[swz(m*16 + rsub + j, col)] = f2b(v);
      }
  }
  __syncthreads();

  // P5: Z = X + mid @ w_down^T -> sN(swz)
  for (int t4 = 0; t4 < 4; ++t4) {
    const int col = (wave*4 + t4)*16 + l15;
    f4v acc[3];
    #pragma unroll
    for (int m = 0; m < 3; ++m) {
      #pragma unroll
      for (int j = 0; j < 4; ++j)
        acc[m][j] = b2f(sX[(m*16 + rsub + j)*XS + col]);
    }
    #pragma unroll
    for (int k = 0; k < 8; ++k) {
      const bf8v b = wfrag<WBF16>(w_down, wbD, col, k*32 + l16);
      #pragma unroll
      for (int m = 0; m < 3; ++m) {
        const bf8v a = *(const bf8v*)(U + swz(m*16 + l15, k*32 + l16));
        acc[m] = mfma16(a, b, acc[m]);
      }
    }
    #pragma unroll
    for (int m = 0; m < 3; ++m)
      #pragma unroll
      for (int j = 0; j < 4; ++j)
        sN[swz(m*16 + rsub + j, col)] = f2b(acc[m][j]);
  }
  __syncthreads();

  // P6: head GEMM on rows 1..32 + MSE vs gathered targets
  float lsum = 0.f;
  for (int t2 = 0; t2 < 2; ++t2) {
    const int col = (wave*2 + t2)*16 + l15;   // 0..127
    const float bh = b_head[col];
    f4v acc[2];
    acc[0] = (f4v){bh,bh,bh,bh}; acc[1] = acc[0];
    #pragma unroll
    for (int k = 0; k < 8; ++k) {
      const bf8v b = wfrag<WBF16>(w_head, wbH, col, k*32 + l16);
      #pragma unroll
      for (int m = 0; m < 2; ++m) {
        const bf8v a = *(const bf8v*)(sN + swz(1 + m*16 + l15, k*32 + l16));
        acc[m] = mfma16(a, b, acc[m]);
      }
    }
    #pragma unroll
    for (int m = 0; m < 2; ++m)
      #pragma unroll
      for (int j = 0; j < 4; ++j) {
        const int row = 1 + m*16 + rsub + j;          // 1..32
        const float tv = target[(size_t)sIdx[row]*DOUT + col];
        const float d = acc[m][j] - tv;
        lsum += d*d;
      }
  }
  lsum = wred(lsum);
  if (lane == 0) sRed[wave] = lsum;
  __syncthreads();
  if (tid == 0)
    partial[bid] = (sRed[0]+sRed[1]+sRed[2]+sRed[3]) * (1.f/(DEG*DOUT));
}

// one-time (per launch) f32 -> bf16 weight conversion into d_ws
__global__ void cvt_w(const float* __restrict__ qkv, const float* __restrict__ o,
                      const float* __restrict__ g, const float* __restrict__ u,
                      const float* __restrict__ dn, const float* __restrict__ hd,
                      unsigned short* __restrict__ out)
{
  const int i = blockIdx.x*NTHREADS + threadIdx.x;
  const int e = i*2;
  if (e >= 491520) return;
  const float* src; int off;
  if      (e < 196608){ src=qkv; off=e; }
  else if (e < 262144){ src=o;  off=e-196608; }
  else if (e < 327680){ src=g;  off=e-262144; }
  else if (e < 393216){ src=u;  off=e-327680; }
  else if (e < 458752){ src=dn; off=e-393216; }
  else                { src=hd; off=e-458752; }
  const float2 v = *(const float2*)(src + off);
  const unsigned int pk = (unsigned int)f2b(v.x) | ((unsigned int)f2b(v.y) << 16);
  *(unsigned int*)(out + e) = pk;
}

__global__ void smtp_reduce(const float* __restrict__ partial, int B, float* __restrict__ out)
{
  __shared__ float sRed[4];
  const int tid = threadIdx.x;
  float s = 0.f;
  for (int i = tid; i < B; i += NTHREADS) s += partial[i];
  s = wred(s);
  if ((tid & 63) == 0) sRed[tid>>6] = s;
  __syncthreads();
  if (tid == 0) out[0] = (sRed[0]+sRed[1]+sRed[2]+sRed[3]) / (float)B;
}

extern "C" void kernel_launch(void* const* d_in, const int* in_sizes, int n_in,
                              void* d_out, int out_size, void* d_ws, size_t ws_size,
                              hipStream_t stream) {
  const float* H        = (const float*)d_in[0];
  const int*   edge     = (const int*)d_in[1];
  const int*   centers  = (const int*)d_in[2];
  const float* target   = (const float*)d_in[3];
  const float* ln_in_w  = (const float*)d_in[5];
  const float* ln1_w    = (const float*)d_in[6];
  const float* ln2_w    = (const float*)d_in[7];
  const float* w_qkv    = (const float*)d_in[8];
  const float* b_qkv    = (const float*)d_in[9];
  const float* w_o      = (const float*)d_in[10];
  const float* b_o      = (const float*)d_in[11];
  const float* w_gate   = (const float*)d_in[12];
  const float* w_up     = (const float*)d_in[13];
  const float* w_down   = (const float*)d_in[14];
  const float* w_head   = (const float*)d_in[15];
  const float* b_head   = (const float*)d_in[16];

  const int B = in_sizes[2];
  const int E = in_sizes[1] / 2;
  const int* dstE = edge + E;

  const size_t WB_ELEMS = 491520;
  const size_t NEED = WB_ELEMS*2 + (size_t)B*4;
  const bool useBf = (ws_size >= NEED);

  if (useBf) {
    unsigned short* wb = (unsigned short*)d_ws;
    float* partial = (float*)((char*)d_ws + WB_ELEMS*2);
    cvt_w<<<960, NTHREADS, 0, stream>>>(w_qkv, w_o, w_gate, w_up, w_down, w_head, wb);
    smtp_center<true><<<B, NTHREADS, 0, stream>>>(H, dstE, centers, target, ln_in_w, ln1_w, ln2_w,
        w_qkv, b_qkv, w_o, b_o, w_gate, w_up, w_down, w_head, b_head, wb, partial);
    smtp_reduce<<<1, NTHREADS, 0, stream>>>(partial, B, (float*)d_out);
  } else {
    float* partial = (float*)d_ws;
    smtp_center<false><<<B, NTHREADS, 0, stream>>>(H, dstE, centers, target, ln_in_w, ln1_w, ln2_w,
        w_qkv, b_qkv, w_o, b_o, w_gate, w_up, w_down, w_head, b_head, (const unsigned short*)d_ws, partial);
    smtp_reduce<<<1, NTHREADS, 0, stream>>>(partial, B, (float*)d_out);
  }
}